// Round 1
// baseline (76.637 us; speedup 1.0000x reference)
//
#include <hip/hip_runtime.h>
#include <math.h>

namespace {
constexpr int kB = 512;
constexpr int kNDist = 511;   // lengths / bonds in plane chain
constexpr int kNAng = 510;
constexpr int kNDih = 509;
constexpr int kNPt = 512;     // points in planar chain
constexpr float kPi = 3.14159265358979323846f;
}

// K1: lengths[j] = mean over batch of distances[:, j]
__global__ void k_lengths(const float* __restrict__ dist, float* __restrict__ len) {
  __shared__ float red[256];
  const int j = blockIdx.x;
  const int t = threadIdx.x;
  float s = dist[(size_t)t * kNDist + j] + dist[(size_t)(t + 256) * kNDist + j];
  red[t] = s;
  __syncthreads();
#pragma unroll
  for (int off = 128; off > 0; off >>= 1) {
    if (t < off) red[t] += red[t + off];
    __syncthreads();
  }
  if (t == 0) len[j] = red[0] * (1.0f / 512.0f);
}

// K2: one block per batch. Phase A: chain_in_plane via parallel scans (LDS).
// Phase B: both dihedral chains (left=threads 0..255, right=256..511) via
// 3x3 rotation-matrix prefix product + float3 prefix sum.
__global__ __launch_bounds__(512) void k_backmap(
    const float* __restrict__ angles,
    const float* __restrict__ dih,
    const float* __restrict__ len,
    float* __restrict__ out) {
  const int b = blockIdx.x;
  const int tid = threadIdx.x;

  __shared__ float s_len[kNPt];
  __shared__ float s_f[kNPt];
  __shared__ float2 s_f2[kNPt];
  __shared__ float s_cx[kNPt];
  __shared__ float s_cy[kNPt];
  __shared__ float s_m[2][256][9];
  __shared__ float s_v[2][256][3];

  if (tid < kNDist) s_len[tid] = len[tid];

  // ---- theta: a_i = sa_i * cumsum(sa_k*(pi - ang_k)); theta = [0, a...] ----
  float t0 = 0.f;
  if (tid < kNAng) {
    const float sa = (tid & 1) ? -1.f : 1.f;
    t0 = sa * (kPi - angles[(size_t)b * kNAng + tid]);
  }
  float v = t0;
  s_f[tid] = v;
  __syncthreads();
#pragma unroll
  for (int off = 1; off < kNPt; off <<= 1) {
    float add = (tid >= off) ? s_f[tid - off] : 0.f;
    __syncthreads();
    v += add;
    s_f[tid] = v;
    __syncthreads();
  }
  float theta = 0.f;
  if (tid >= 1 && tid < kNDist) {
    const float sa = ((tid - 1) & 1) ? -1.f : 1.f;
    theta = sa * s_f[tid - 1];
  }
  // ---- dx, dy then prefix sums -> planar cart (z=0) ----
  float dxv = 0.f, dyv = 0.f;
  if (tid < kNDist) {
    float sn, cs;
    sincosf(theta, &sn, &cs);
    const float L = s_len[tid];
    const float sg = (tid & 1) ? -1.f : 1.f;
    dxv = L * cs;
    dyv = L * sn * sg;
  }
  float2 v2 = make_float2(dxv, dyv);
  s_f2[tid] = v2;
  __syncthreads();
#pragma unroll
  for (int off = 1; off < kNPt; off <<= 1) {
    float ax = 0.f, ay = 0.f;
    if (tid >= off) { float2 w = s_f2[tid - off]; ax = w.x; ay = w.y; }
    __syncthreads();
    v2.x += ax; v2.y += ay;
    s_f2[tid] = v2;
    __syncthreads();
  }
  float px = 0.f, py = 0.f;
  if (tid >= 1) { float2 w = s_f2[tid - 1]; px = w.x; py = w.y; }
  s_cx[tid] = px;
  s_cy[tid] = py;
  __syncthreads();

  // ---- two chain rebuilds ----
  // left:  r0[k] = cart[256-k], k=0..256; phi_i = dih[254-i]+pi, i<255
  // right: r0[k] = cart[256+k], k=0..255; phi_i = dih[255+i]+pi, i<254
  const int side = tid >> 8;  // 0 = left, 1 = right
  const int k = tid & 255;
  const int nb = side ? 255 : 256;  // bonds
  const int ng = side ? 254 : 255;  // rotation matrices

  float bx = 0.f, by = 0.f;
  if (k < nb) {
    const int i0 = side ? (256 + k) : (256 - k);
    const int i1 = side ? (257 + k) : (255 - k);
    bx = s_cx[i1] - s_cx[i0];
    by = s_cy[i1] - s_cy[i0];
  }

  // G_k = rodrigues(u_k, phi_k); u_k planar => uz = 0
  float m0 = 1.f, m1 = 0.f, m2 = 0.f, m3 = 0.f, m4 = 1.f, m5 = 0.f,
        m6 = 0.f, m7 = 0.f, m8 = 1.f;
  if (k < ng) {
    const float phi = side ? (dih[(size_t)b * kNDih + 255 + k] + kPi)
                           : (dih[(size_t)b * kNDih + 254 - k] + kPi);
    const float rn = rsqrtf(bx * bx + by * by);
    const float ax = bx * rn, ay = by * rn;
    float sp, cp;
    sincosf(phi, &sp, &cp);
    const float omc = 1.f - cp;
    m0 = cp + omc * ax * ax;  m1 = omc * ax * ay;      m2 = sp * ay;
    m3 = omc * ax * ay;       m4 = cp + omc * ay * ay; m5 = -sp * ax;
    m6 = -sp * ay;            m7 = sp * ax;            m8 = cp;
  }
  {
    float* M = s_m[side][k];
    M[0]=m0; M[1]=m1; M[2]=m2; M[3]=m3; M[4]=m4; M[5]=m5; M[6]=m6; M[7]=m7; M[8]=m8;
  }
  __syncthreads();
  // inclusive non-commutative scan: S_k = G_0 * ... * G_k
#pragma unroll
  for (int off = 1; off < 256; off <<= 1) {
    float n0=0,n1=0,n2=0,n3=0,n4=0,n5=0,n6=0,n7=0,n8=0;
    const bool has = (k >= off);
    if (has) {
      const float* N = s_m[side][k - off];
      n0=N[0]; n1=N[1]; n2=N[2]; n3=N[3]; n4=N[4]; n5=N[5]; n6=N[6]; n7=N[7]; n8=N[8];
    }
    __syncthreads();
    if (has) {
      const float a0 = n0*m0 + n1*m3 + n2*m6;
      const float a1 = n0*m1 + n1*m4 + n2*m7;
      const float a2 = n0*m2 + n1*m5 + n2*m8;
      const float a3 = n3*m0 + n4*m3 + n5*m6;
      const float a4 = n3*m1 + n4*m4 + n5*m7;
      const float a5 = n3*m2 + n4*m5 + n5*m8;
      const float a6 = n6*m0 + n7*m3 + n8*m6;
      const float a7 = n6*m1 + n7*m4 + n8*m7;
      const float a8 = n6*m2 + n7*m5 + n8*m8;
      m0=a0; m1=a1; m2=a2; m3=a3; m4=a4; m5=a5; m6=a6; m7=a7; m8=a8;
    }
    float* M = s_m[side][k];
    M[0]=m0; M[1]=m1; M[2]=m2; M[3]=m3; M[4]=m4; M[5]=m5; M[6]=m6; M[7]=m7; M[8]=m8;
    __syncthreads();
  }

  // rotated bonds c_k = W_k * b0_k, W_k = S_{k-1}, W_0 = I (bz = 0)
  float cx = 0.f, cy = 0.f, cz = 0.f;
  if (k < nb) {
    if (k == 0) {
      cx = bx; cy = by; cz = 0.f;
    } else {
      const float* S = s_m[side][k - 1];
      cx = S[0]*bx + S[1]*by;
      cy = S[3]*bx + S[4]*by;
      cz = S[6]*bx + S[7]*by;
    }
  }
  // float3 inclusive scan per side -> p_{k+1} = r0_0 + I_k
  float vx = cx, vy = cy, vz = cz;
  {
    float* V = s_v[side][k];
    V[0]=vx; V[1]=vy; V[2]=vz;
  }
  __syncthreads();
#pragma unroll
  for (int off = 1; off < 256; off <<= 1) {
    float ax=0.f, ay=0.f, az=0.f;
    if (k >= off) {
      const float* W = s_v[side][k - off];
      ax=W[0]; ay=W[1]; az=W[2];
    }
    __syncthreads();
    vx+=ax; vy+=ay; vz+=az;
    float* V = s_v[side][k];
    V[0]=vx; V[1]=vy; V[2]=vz;
    __syncthreads();
  }

  // ---- output assembly (flip(new_l) ++ new_r[3:]) ----
  // rows 0..255:  p_left_{256-row}  (thread k writes row 255-k, p_{k+1})
  // row 256:      cart[256]   row 257: cart[257]
  // rows 258..511: p_right_{row-256} (thread k=1..254 writes row 257+k)
  const float bpx = s_cx[256], bpy = s_cy[256];
  const float ox = bpx + vx, oy = bpy + vy, oz = vz;
  float* outb = out + (size_t)b * 512 * 3;
  if (side == 0) {
    const int row = 255 - k;
    outb[row*3+0] = ox; outb[row*3+1] = oy; outb[row*3+2] = oz;
  } else {
    if (k >= 1 && k <= 254) {
      const int row = 257 + k;
      outb[row*3+0] = ox; outb[row*3+1] = oy; outb[row*3+2] = oz;
    }
    if (k == 0) {
      outb[256*3+0] = bpx; outb[256*3+1] = bpy; outb[256*3+2] = 0.f;
    }
    if (k == 255) {
      outb[257*3+0] = s_cx[257]; outb[257*3+1] = s_cy[257]; outb[257*3+2] = 0.f;
    }
  }
}

extern "C" void kernel_launch(void* const* d_in, const int* in_sizes, int n_in,
                              void* d_out, int out_size, void* d_ws, size_t ws_size,
                              hipStream_t stream) {
  const float* distances = (const float*)d_in[0];
  const float* angles    = (const float*)d_in[1];
  const float* dihedrals = (const float*)d_in[2];
  float* lengths = (float*)d_ws;  // 511 floats of scratch
  float* out = (float*)d_out;
  k_lengths<<<kNDist, 256, 0, stream>>>(distances, lengths);
  k_backmap<<<kB, 512, 0, stream>>>(angles, dihedrals, lengths, out);
}